// Round 16
// baseline (338.354 us; speedup 1.0000x reference)
//
#include <hip/hip_runtime.h>
#include <cstdint>

constexpr int DD = 512;       // feature dim
constexpr int KK = 8192;      // codebook size
constexpr int NROWS = 16384;  // x rows
#define MARGIN 1.0f

// ws layout: Axp (fp16 X) | Bfp (fp16 CB) | csq | keys
constexpr size_t AX_ELEMS = (size_t)NROWS * DD;    // ushort
constexpr size_t BF_ELEMS = (size_t)KK * DD;       // ushort
constexpr size_t KEY_ELEMS = (size_t)NROWS * 128;  // ull (2 per 128-col block)
constexpr size_t WS_NEEDED =
    AX_ELEMS * 2 + BF_ELEMS * 2 + (size_t)KK * 4 + KEY_ELEMS * 8;  // 41,975,808 (< proven 50.4MB)

typedef __attribute__((ext_vector_type(8))) short short8v;
typedef __attribute__((ext_vector_type(8))) _Float16 half8v;
typedef __attribute__((ext_vector_type(4))) float floatx4;
typedef unsigned long long ull;

__device__ __forceinline__ ull umin64(ull a, ull b) { return a < b ? a : b; }
__device__ __forceinline__ uint32_t fsort(float f) {
  uint32_t u = __float_as_uint(f);
  return (u & 0x80000000u) ? ~u : (u | 0x80000000u);
}
__device__ __forceinline__ float funsort(uint32_t u) {
  uint32_t f = (u & 0x80000000u) ? (u ^ 0x80000000u) : ~u;
  return __uint_as_float(f);
}

// async global->LDS, 16B per lane; LDS dest is wave-uniform base + lane*16
__device__ __forceinline__ void gl_lds16(const ushort* g, ushort* l) {
  __builtin_amdgcn_global_load_lds(
      (const __attribute__((address_space(1))) unsigned int*)g,
      (__attribute__((address_space(3))) unsigned int*)l, 16, 0, 0);
}

// numpy-style pairwise sum of squares over 128 contiguous floats
__device__ __forceinline__ float pairwise128_sq(const float* __restrict__ p) {
#pragma clang fp contract(off)
  float r[8];
  {
    float4 a = ((const float4*)p)[0];
    float4 b = ((const float4*)p)[1];
    r[0] = a.x * a.x; r[1] = a.y * a.y; r[2] = a.z * a.z; r[3] = a.w * a.w;
    r[4] = b.x * b.x; r[5] = b.y * b.y; r[6] = b.z * b.z; r[7] = b.w * b.w;
  }
  for (int i = 2; i < 32; i += 2) {
    float4 a = ((const float4*)p)[i];
    float4 b = ((const float4*)p)[i + 1];
    r[0] = r[0] + a.x * a.x; r[1] = r[1] + a.y * a.y;
    r[2] = r[2] + a.z * a.z; r[3] = r[3] + a.w * a.w;
    r[4] = r[4] + b.x * b.x; r[5] = r[5] + b.y * b.y;
    r[6] = r[6] + b.z * b.z; r[7] = r[7] + b.w * b.w;
  }
  return ((r[0] + r[1]) + (r[2] + r[3])) + ((r[4] + r[5]) + (r[6] + r[7]));
}

// ---------------- pre-pass: fp32 -> fp16 cast (flat) ----------------
__global__ __launch_bounds__(256)
void cast16_kernel(const float* __restrict__ src, ushort* __restrict__ dst) {
  int idx = blockIdx.x * 256 + threadIdx.x;  // one float4 per thread
  float4 v = *(const float4*)(src + (size_t)idx * 4);
  ushort h[4];
  float vv[4] = {v.x, v.y, v.z, v.w};
#pragma unroll
  for (int i = 0; i < 4; ++i) h[i] = __builtin_bit_cast(ushort, (_Float16)vv[i]);
  *(ushort4*)(dst + (size_t)idx * 4) = make_ushort4(h[0], h[1], h[2], h[3]);
}

// ---------------- pre-pass: c_sq (numpy pairwise) ----------------
__global__ __launch_bounds__(256)
void csq_kernel(const float* __restrict__ CB, float* __restrict__ csq) {
  __shared__ float cblk[64][4];
  int t = threadIdx.x;
  int r0 = blockIdx.x * 64;
  int row = t >> 2, blk = t & 3;
  cblk[row][blk] = pairwise128_sq(CB + (size_t)(r0 + row) * DD + blk * 128);
  __syncthreads();
  if (t < 64) {
#pragma clang fp contract(off)
    csq[r0 + t] = (cblk[t][0] + cblk[t][1]) + (cblk[t][2] + cblk[t][3]);
  }
}

// ------------- screening GEMM (fp16 single, K=512) -------------
// R14 structure (L2-aware remap, epilogue v2, 512thr/8 waves, proven sync
// skeleton) with A read DIRECTLY global->VGPR (L2-resident, 64B-line
// coalesced fragments): A's LDS reads/writes/DMA vanish -> LDS pipe
// ~150us -> ~96us. B staging/readout unchanged.
__global__ __launch_bounds__(512, 6)
void vq_screen16_kernel(const ushort* __restrict__ Axp, const ushort* __restrict__ Bfp,
                        const float* __restrict__ csq, ull* __restrict__ keys) {
  __shared__ ushort BS[128 * 64];
  __shared__ ull mb[128][2][2];

  const int t = threadIdx.x;
  const int L = t & 63;
  const int w = t >> 6;            // 0..7
  const int wr = (w & 3) * 32;     // row group (4 x 32 rows)
  const int wc = (w >> 2) * 64;    // col half (2 x 64 cols)
  const int seg = L >> 4;
  const int l15 = L & 15;

  // L2-aware bijective remap: bid -> (xcd, rg, cbi, ri)
  const int bid = blockIdx.x;
  const int xcd = bid & 7;
  const int loc = bid >> 3;            // 0..1023
  const int ri  = loc & 7;
  const int cbi = (loc >> 3) & 7;
  const int rg  = loc >> 6;            // 0..15
  const int rb  = rg * 8 + ri;         // 0..127
  const int cb  = xcd * 8 + cbi;       // 0..63
  const size_t r0 = (size_t)rb * 128, c0 = (size_t)cb * 128;

  // B staging (same proven map): wave w covers B rows [w*16, w*16+16).
  // lane l -> dest row base+l>>3, granule l&7; source supplies the
  // inverse-swizzled granule (l&7)^(l>>3) so swizzled READS stay valid.
  const int lrow = L >> 3;
  const int lgr = (L & 7) ^ lrow;
  const ushort* srcB0 = Bfp + (c0 + w * 16 + lrow) * DD + lgr * 8;

  // A per-lane global fragment pointers (k offset kc*64 + s*32 added in-loop)
  const ushort* pa0 = Axp + (r0 + wr + l15) * DD + seg * 8;
  const ushort* pa1 = pa0 + (size_t)16 * DD;

  // loop-invariant B LDS read offsets
  int boff[2][4];
#pragma unroll
  for (int s = 0; s < 2; ++s) {
    const int kcol = s * 4 + seg;
#pragma unroll
    for (int n = 0; n < 4; ++n) {
      const int cl = wc + n * 16 + l15;
      boff[s][n] = cl * 64 + ((kcol * 8) ^ ((cl & 7) * 8));
    }
  }

  floatx4 acc[2][4];
#pragma unroll
  for (int m = 0; m < 2; ++m)
#pragma unroll
    for (int n = 0; n < 4; ++n) acc[m][n] = (floatx4){0.f, 0.f, 0.f, 0.f};

  for (int kc = 0; kc < 8; ++kc) {
    if (kc) __syncthreads();  // all readers done before clobbering BS
    // stage B tile chunk (2 x 1KB DMA per wave)
#pragma unroll
    for (int j = 0; j < 2; ++j)
      gl_lds16(srcB0 + (size_t)j * 8 * DD + kc * 64, &BS[(w * 16 + j * 8) * 64]);
    // A fragments for this step: global->reg (L2-hit), complete at the barrier
    half8v a[2][2];
#pragma unroll
    for (int s = 0; s < 2; ++s) {
      a[0][s] = *(const half8v*)(pa0 + kc * 64 + s * 32);
      a[1][s] = *(const half8v*)(pa1 + kc * 64 + s * 32);
    }
    __syncthreads();  // vmcnt(0)+lgkmcnt(0): BS staged, A regs ready

#pragma unroll
    for (int s = 0; s < 2; ++s) {
      half8v bf[4];
#pragma unroll
      for (int n = 0; n < 4; ++n) bf[n] = *(const half8v*)&BS[boff[s][n]];
#pragma unroll
      for (int m = 0; m < 2; ++m)
#pragma unroll
        for (int n = 0; n < 4; ++n)
          acc[m][n] = __builtin_amdgcn_mfma_f32_16x16x32_f16(a[m][s], bf[n], acc[m][n], 0, 0, 0);
    }
  }

  // ---- epilogue v2: float-domain per-row best-2, owner-writes via ballot ----
  float cq[4];
#pragma unroll
  for (int n = 0; n < 4; ++n) cq[n] = csq[c0 + wc + n * 16 + l15];
  const float INF = __builtin_inff();

#pragma unroll
  for (int m = 0; m < 2; ++m) {
#pragma unroll
    for (int i = 0; i < 4; ++i) {
      float q0 = __builtin_fmaf(-2.f, acc[m][0][i], cq[0]);
      float q1 = __builtin_fmaf(-2.f, acc[m][1][i], cq[1]);
      float q2 = __builtin_fmaf(-2.f, acc[m][2][i], cq[2]);
      float q3 = __builtin_fmaf(-2.f, acc[m][3][i], cq[3]);
      const int rl = wr + m * 16 + seg * 4 + i;

      // best-1 across the 16 lanes (f32 shuffles)
      float qm = fminf(fminf(q0, q1), fminf(q2, q3));
#pragma unroll
      for (int mask = 1; mask <= 8; mask <<= 1) qm = fminf(qm, __shfl_xor(qm, mask, 64));
      int n1 = (q0 == qm) ? 0 : (q1 == qm) ? 1 : (q2 == qm) ? 2 : (q3 == qm) ? 3 : 4;
      ull bal = __ballot(n1 < 4);
      int fl = __ffsll((bal >> (seg * 16)) & 0xFFFFull) - 1;
      const bool own1 = (l15 == fl);
      if (own1) {
        int col = (int)c0 + wc + n1 * 16 + l15;
        mb[rl][w >> 2][0] = ((ull)fsort(qm) << 32) | (uint32_t)col;
      }
      // best-2: owner masks its matched element, repeat
      float e0 = q0, e1 = q1, e2 = q2, e3 = q3;
      if (own1) {
        if (n1 == 0) e0 = INF; else if (n1 == 1) e1 = INF;
        else if (n1 == 2) e2 = INF; else e3 = INF;
      }
      float q2m = fminf(fminf(e0, e1), fminf(e2, e3));
#pragma unroll
      for (int mask = 1; mask <= 8; mask <<= 1) q2m = fminf(q2m, __shfl_xor(q2m, mask, 64));
      int n2 = (e0 == q2m) ? 0 : (e1 == q2m) ? 1 : (e2 == q2m) ? 2 : (e3 == q2m) ? 3 : 4;
      ull bal2 = __ballot(n2 < 4);
      int fl2 = __ffsll((bal2 >> (seg * 16)) & 0xFFFFull) - 1;
      if (l15 == fl2) {
        int col = (int)c0 + wc + n2 * 16 + l15;
        mb[rl][w >> 2][1] = ((ull)fsort(q2m) << 32) | (uint32_t)col;
      }
    }
  }
  __syncthreads();
  if (t < 128) {
    ull a1 = mb[t][0][0], a2 = mb[t][0][1];
    ull b1 = mb[t][1][0], b2 = mb[t][1][1];
    ull k1, k2;
    if (a1 < b1) { k1 = a1; k2 = umin64(a2, b1); }
    else { k1 = b1; k2 = umin64(b2, a1); }
    keys[(r0 + t) * 128 + cb * 2 + 0] = k1;
    keys[(r0 + t) * 128 + cb * 2 + 1] = k2;
  }
}

// ------- reduce: ballot margin-count, skip-if-unique, wave-parallel rescore -------
__global__ __launch_bounds__(256)
void vq_reduce_kernel(const float* __restrict__ X, const float* __restrict__ CB,
                      const float* __restrict__ csq, const ull* __restrict__ keys,
                      float* __restrict__ out) {
  __shared__ int bidx[4];
  const int t = threadIdx.x;
  const int L = t & 63;
  const int w = t >> 6;
  const size_t row = (size_t)blockIdx.x * 4 + w;
  ulonglong2 kk = *(const ulonglong2*)(keys + row * 128 + L * 2);

  ull kmin = umin64(kk.x, kk.y);
#pragma unroll
  for (int m = 32; m; m >>= 1) {
    ull o = __shfl_xor(kmin, m, 64);
    if (o < kmin) kmin = o;
  }
  const float qcut = funsort((uint32_t)(kmin >> 32)) + MARGIN;

  const bool q0 = funsort((uint32_t)(kk.x >> 32)) <= qcut;
  const bool q1 = funsort((uint32_t)(kk.y >> 32)) <= qcut;
  const ull b0 = __ballot(q0);
  const ull b1 = __ballot(q1);
  const int total = __popcll(b0) + __popcll(b1);

  int winner;
  if (total <= 1) {
    winner = (int)(kmin & 0xffffffffu);
  } else {
    const float* xp = X + row * DD;
    const float4 xa = ((const float4*)xp)[L * 2];
    const float4 xb = ((const float4*)xp)[L * 2 + 1];
    ull bestE = ~0ull;
#pragma unroll
    for (int pass = 0; pass < 2; ++pass) {
      ull mask = pass ? b1 : b0;
      while (mask) {
        const int lane = __ffsll(mask) - 1;
        mask &= mask - 1;
        const ull key = __shfl(pass ? kk.y : kk.x, lane, 64);
        const int idx = (int)(key & 0xffffffffu);
        const float* cp = CB + (size_t)idx * DD;
        const float4 ca = ((const float4*)cp)[L * 2];
        const float4 cbv = ((const float4*)cp)[L * 2 + 1];
        float p = 0.f;
        p = __builtin_fmaf(xa.x, ca.x, p);
        p = __builtin_fmaf(xa.y, ca.y, p);
        p = __builtin_fmaf(xa.z, ca.z, p);
        p = __builtin_fmaf(xa.w, ca.w, p);
        p = __builtin_fmaf(xb.x, cbv.x, p);
        p = __builtin_fmaf(xb.y, cbv.y, p);
        p = __builtin_fmaf(xb.z, cbv.z, p);
        p = __builtin_fmaf(xb.w, cbv.w, p);
#pragma unroll
        for (int m = 32; m; m >>= 1) p += __shfl_xor(p, m, 64);
        const float q = csq[idx] - 2.0f * p;
        const ull ek = ((ull)fsort(q) << 32) | (uint32_t)idx;
        bestE = umin64(bestE, ek);
      }
    }
    winner = (int)(bestE & 0xffffffffu);
  }
  if (L == 0) bidx[w] = winner;
  __syncthreads();

  const size_t r0 = (size_t)blockIdx.x * 4;
#pragma unroll
  for (int it = 0; it < 2; ++it) {
    int idx = t + it * 256;
    int rw = idx >> 7, c4 = idx & 127;
    float4 v = *(const float4*)(CB + (size_t)bidx[rw] * DD + c4 * 4);
    *(float4*)(out + (r0 + rw) * DD + c4 * 4) = v;
  }
}

// =================== fallback path (round-2, ws-free, replay-proven) ===================
constexpr int FBM = 128, FBN = 128, FBK = 32, FNT = 256;
constexpr int FKSPLIT = 4;
constexpr int FKPB = KK / FKSPLIT;

__global__ __launch_bounds__(FNT)
void vq_partial_kernel(const float* __restrict__ X, const float* __restrict__ CB,
                       float* __restrict__ keyout) {
  __shared__ float Xs[FBK][FBM + 4];
  __shared__ float Cs[FBK][FBN + 4];
  __shared__ float xblk[FBM][4];
  __shared__ float cblk[FBN][4];
  __shared__ float xsq[FBM];
  __shared__ float csq[FBN];

  const int t = threadIdx.x;
  const int tx = t & 15;
  const int ty = t >> 4;
  const int bid = blockIdx.x;
  const int xcd = bid & 7;
  const int loc = bid >> 3;
  const int ksplit = xcd >> 1;
  const int rowblk = (xcd & 1) * 64 + loc;
  const long r0 = (long)rowblk * FBM;
  const int kbase = ksplit * FKPB;

#pragma unroll
  for (int it = 0; it < 2; ++it) {
    int task = t + it * FNT;
    int row = task >> 2, blk = task & 3;
    xblk[row][blk] = pairwise128_sq(X + (r0 + row) * DD + blk * 128);
  }
  __syncthreads();
  if (t < FBM) {
#pragma clang fp contract(off)
    xsq[t] = (xblk[t][0] + xblk[t][1]) + (xblk[t][2] + xblk[t][3]);
  }

  uint64_t bestKey[8];
#pragma unroll
  for (int i = 0; i < 8; ++i) bestKey[i] = ~0ull;

  float4 xr[4], cr[4];
  for (int kt = 0; kt < FKPB / FBN; ++kt) {
    const int k0 = kbase + kt * FBN;
    __syncthreads();
#pragma unroll
    for (int it = 0; it < 4; ++it) {
      int idx = t + it * FNT;
      int row = idx >> 3, dg = (idx & 7) * 4;
      xr[it] = *(const float4*)(X + (r0 + row) * DD + dg);
      cr[it] = *(const float4*)(CB + (long)(k0 + row) * DD + dg);
    }
#pragma unroll
    for (int it = 0; it < 2; ++it) {
      int task = t + it * FNT;
      int cw = task >> 2, blk = task & 3;
      cblk[cw][blk] = pairwise128_sq(CB + (long)(k0 + cw) * DD + blk * 128);
    }
    __syncthreads();
    if (t < FBN) {
#pragma clang fp contract(off)
      csq[t] = (cblk[t][0] + cblk[t][1]) + (cblk[t][2] + cblk[t][3]);
    }

    float acc[8][8];
#pragma unroll
    for (int i = 0; i < 8; ++i)
#pragma unroll
      for (int j = 0; j < 8; ++j) acc[i][j] = 0.0f;

    for (int dc = 0; dc < DD; dc += FBK) {
#pragma unroll
      for (int it = 0; it < 4; ++it) {
        int idx = t + it * FNT;
        int row = idx >> 3, dg = (idx & 7) * 4;
        Xs[dg + 0][row] = xr[it].x; Xs[dg + 1][row] = xr[it].y;
        Xs[dg + 2][row] = xr[it].z; Xs[dg + 3][row] = xr[it].w;
        Cs[dg + 0][row] = cr[it].x; Cs[dg + 1][row] = cr[it].y;
        Cs[dg + 2][row] = cr[it].z; Cs[dg + 3][row] = cr[it].w;
      }
      if (dc + FBK < DD) {
#pragma unroll
        for (int it = 0; it < 4; ++it) {
          int idx = t + it * FNT;
          int row = idx >> 3, dg = (idx & 7) * 4 + dc + FBK;
          xr[it] = *(const float4*)(X + (r0 + row) * DD + dg);
          cr[it] = *(const float4*)(CB + (long)(k0 + row) * DD + dg);
        }
      }
      __syncthreads();
#pragma unroll 4
      for (int d = 0; d < FBK; ++d) {
        const float4 xa0 = *(const float4*)&Xs[d][ty * 4];
        const float4 xa1 = *(const float4*)&Xs[d][64 + ty * 4];
        const float4 cb0 = *(const float4*)&Cs[d][tx * 4];
        const float4 cb1 = *(const float4*)&Cs[d][64 + tx * 4];
        const float xv[8] = {xa0.x, xa0.y, xa0.z, xa0.w, xa1.x, xa1.y, xa1.z, xa1.w};
        const float cv[8] = {cb0.x, cb0.y, cb0.z, cb0.w, cb1.x, cb1.y, cb1.z, cb1.w};
#pragma unroll
        for (int i = 0; i < 8; ++i)
#pragma unroll
          for (int j = 0; j < 8; ++j)
            acc[i][j] = __builtin_fmaf(xv[i], cv[j], acc[i][j]);
      }
      __syncthreads();
    }
    {
#pragma clang fp contract(off)
#pragma unroll
      for (int i = 0; i < 8; ++i) {
        int rl = (i < 4) ? (ty * 4 + i) : (64 + ty * 4 + (i - 4));
        float xsv = xsq[rl];
#pragma unroll
        for (int j = 0; j < 8; ++j) {
          int cl = (j < 4) ? (tx * 4 + j) : (64 + tx * 4 + (j - 4));
          float m = 2.0f * acc[i][j];
          float t1 = xsv - m;
          float dist = t1 + csq[cl];
          uint64_t key = ((uint64_t)fsort(dist) << 32) | (uint32_t)(k0 + cl);
          if (key < bestKey[i]) bestKey[i] = key;
        }
      }
    }
  }
#pragma unroll
  for (int i = 0; i < 8; ++i) {
    ull k = bestKey[i];
#pragma unroll
    for (int m = 1; m <= 8; m <<= 1) {
      ull o = __shfl_xor(k, m, 64);
      if (o < k) k = o;
    }
    if (tx == 0) {
      int rl = (i < 4) ? (ty * 4 + i) : (64 + ty * 4 + (i - 4));
      *(ull*)(keyout + (r0 + rl) * DD + ksplit * 2) = k;
    }
  }
}

__global__ __launch_bounds__(FNT)
void vq_reduce_gather_kernel(const float* __restrict__ CB, float* __restrict__ out) {
  __shared__ int bidx[32];
  const int t = threadIdx.x;
  const long r0 = (long)blockIdx.x * 32;
  if (t < 32) {
    const ull* kp = (const ull*)(out + (r0 + t) * DD);
    ull k = kp[0];
#pragma unroll
    for (int s = 1; s < FKSPLIT; ++s) k = umin64(k, kp[s]);
    bidx[t] = (int)(k & 0xffffffffu);
  }
  __syncthreads();
#pragma unroll
  for (int it = 0; it < 16; ++it) {
    int idx = t + it * FNT;
    int row = idx >> 7, c4 = idx & 127;
    const float4 v = *(const float4*)(CB + (long)bidx[row] * DD + c4 * 4);
    *(float4*)(out + (r0 + row) * DD + c4 * 4) = v;
  }
}

extern "C" void kernel_launch(void* const* d_in, const int* in_sizes, int n_in,
                              void* d_out, int out_size, void* d_ws, size_t ws_size,
                              hipStream_t stream) {
  const float* X = (const float*)d_in[0];   // [16384, 512]
  const float* CB = (const float*)d_in[1];  // [8192, 512]
  float* out = (float*)d_out;

  if (ws_size >= WS_NEEDED) {
    ushort* Axp = (ushort*)d_ws;
    ushort* Bfp = Axp + AX_ELEMS;
    float* csqp = (float*)(Bfp + BF_ELEMS);
    ull* keys = (ull*)(csqp + KK);
    hipLaunchKernelGGL(cast16_kernel, dim3(NROWS * DD / 4 / 256), dim3(256), 0, stream, X, Axp);
    hipLaunchKernelGGL(cast16_kernel, dim3(KK * DD / 4 / 256), dim3(256), 0, stream, CB, Bfp);
    hipLaunchKernelGGL(csq_kernel, dim3(KK / 64), dim3(256), 0, stream, CB, csqp);
    hipLaunchKernelGGL(vq_screen16_kernel, dim3((NROWS / 128) * (KK / 128)), dim3(512), 0, stream,
                       Axp, Bfp, csqp, keys);
    hipLaunchKernelGGL(vq_reduce_kernel, dim3(NROWS / 4), dim3(256), 0, stream,
                       X, CB, csqp, keys, out);
  } else {
    hipLaunchKernelGGL(vq_partial_kernel, dim3(512), dim3(FNT), 0, stream, X, CB, out);
    hipLaunchKernelGGL(vq_reduce_gather_kernel, dim3(NROWS / 32), dim3(FNT), 0, stream, CB, out);
  }
}

// Round 17
// 241.018 us; speedup vs baseline: 1.4039x; 1.4039x over previous
//
#include <hip/hip_runtime.h>
#include <cstdint>

constexpr int DD = 512;       // feature dim
constexpr int KK = 8192;      // codebook size
constexpr int NROWS = 16384;  // x rows
#define MARGIN 1.0f

// ws layout: Axp (fp16 X) | Bfp (fp16 CB) | csq | keys
constexpr size_t AX_ELEMS = (size_t)NROWS * DD;    // ushort
constexpr size_t BF_ELEMS = (size_t)KK * DD;       // ushort
constexpr size_t KEY_ELEMS = (size_t)NROWS * 128;  // ull (2 per 128-col block)
constexpr size_t WS_NEEDED =
    AX_ELEMS * 2 + BF_ELEMS * 2 + (size_t)KK * 4 + KEY_ELEMS * 8;  // 41,975,808 (< proven 50.4MB)

typedef __attribute__((ext_vector_type(8))) short short8v;
typedef __attribute__((ext_vector_type(8))) _Float16 half8v;
typedef __attribute__((ext_vector_type(8))) unsigned short ushort8v;
typedef __attribute__((ext_vector_type(4))) float floatx4;
typedef unsigned long long ull;

__device__ __forceinline__ ull umin64(ull a, ull b) { return a < b ? a : b; }
__device__ __forceinline__ uint32_t fsort(float f) {
  uint32_t u = __float_as_uint(f);
  return (u & 0x80000000u) ? ~u : (u | 0x80000000u);
}
__device__ __forceinline__ float funsort(uint32_t u) {
  uint32_t f = (u & 0x80000000u) ? (u ^ 0x80000000u) : ~u;
  return __uint_as_float(f);
}

// async global->LDS, 16B per lane; LDS dest is wave-uniform base + lane*16
__device__ __forceinline__ void gl_lds16(const ushort* g, ushort* l) {
  __builtin_amdgcn_global_load_lds(
      (const __attribute__((address_space(1))) unsigned int*)g,
      (__attribute__((address_space(3))) unsigned int*)l, 16, 0, 0);
}

// numpy-style pairwise sum of squares over 128 contiguous floats
__device__ __forceinline__ float pairwise128_sq(const float* __restrict__ p) {
#pragma clang fp contract(off)
  float r[8];
  {
    float4 a = ((const float4*)p)[0];
    float4 b = ((const float4*)p)[1];
    r[0] = a.x * a.x; r[1] = a.y * a.y; r[2] = a.z * a.z; r[3] = a.w * a.w;
    r[4] = b.x * b.x; r[5] = b.y * b.y; r[6] = b.z * b.z; r[7] = b.w * b.w;
  }
  for (int i = 2; i < 32; i += 2) {
    float4 a = ((const float4*)p)[i];
    float4 b = ((const float4*)p)[i + 1];
    r[0] = r[0] + a.x * a.x; r[1] = r[1] + a.y * a.y;
    r[2] = r[2] + a.z * a.z; r[3] = r[3] + a.w * a.w;
    r[4] = r[4] + b.x * b.x; r[5] = r[5] + b.y * b.y;
    r[6] = r[6] + b.z * b.z; r[7] = r[7] + b.w * b.w;
  }
  return ((r[0] + r[1]) + (r[2] + r[3])) + ((r[4] + r[5]) + (r[6] + r[7]));
}

// ---------------- pre-pass: X fp32 -> fp16 cast (flat) ----------------
__global__ __launch_bounds__(256)
void cast16_kernel(const float* __restrict__ src, ushort* __restrict__ dst) {
  int idx = blockIdx.x * 256 + threadIdx.x;  // one float4 per thread
  float4 v = *(const float4*)(src + (size_t)idx * 4);
  ushort h[4];
  float vv[4] = {v.x, v.y, v.z, v.w};
#pragma unroll
  for (int i = 0; i < 4; ++i) h[i] = __builtin_bit_cast(ushort, (_Float16)vv[i]);
  *(ushort4*)(dst + (size_t)idx * 4) = make_ushort4(h[0], h[1], h[2], h[3]);
}

// ------- fused pre-pass: CB fp32 -> fp16 cast + c_sq (numpy pairwise) -------
// One CB read serves both. csq arithmetic sequence identical to the proven
// csq_kernel; the cast is independent per element.
__global__ __launch_bounds__(256)
void castB_csq_kernel(const float* __restrict__ CB, ushort* __restrict__ Bfp,
                      float* __restrict__ csq) {
  __shared__ float cblk[64][4];
  int t = threadIdx.x;
  int r0 = blockIdx.x * 64;
  int row = t >> 2, blk = t & 3;
  const float* p = CB + (size_t)(r0 + row) * DD + blk * 128;
  ushort* q = Bfp + (size_t)(r0 + row) * DD + blk * 128;
  float r[8];
  {
#pragma clang fp contract(off)
    float4 a = ((const float4*)p)[0];
    float4 b = ((const float4*)p)[1];
    r[0] = a.x * a.x; r[1] = a.y * a.y; r[2] = a.z * a.z; r[3] = a.w * a.w;
    r[4] = b.x * b.x; r[5] = b.y * b.y; r[6] = b.z * b.z; r[7] = b.w * b.w;
    ushort8v h = {__builtin_bit_cast(ushort, (_Float16)a.x), __builtin_bit_cast(ushort, (_Float16)a.y),
                  __builtin_bit_cast(ushort, (_Float16)a.z), __builtin_bit_cast(ushort, (_Float16)a.w),
                  __builtin_bit_cast(ushort, (_Float16)b.x), __builtin_bit_cast(ushort, (_Float16)b.y),
                  __builtin_bit_cast(ushort, (_Float16)b.z), __builtin_bit_cast(ushort, (_Float16)b.w)};
    *(ushort8v*)q = h;
  }
  for (int i = 2; i < 32; i += 2) {
#pragma clang fp contract(off)
    float4 a = ((const float4*)p)[i];
    float4 b = ((const float4*)p)[i + 1];
    r[0] = r[0] + a.x * a.x; r[1] = r[1] + a.y * a.y;
    r[2] = r[2] + a.z * a.z; r[3] = r[3] + a.w * a.w;
    r[4] = r[4] + b.x * b.x; r[5] = r[5] + b.y * b.y;
    r[6] = r[6] + b.z * b.z; r[7] = r[7] + b.w * b.w;
    ushort8v h = {__builtin_bit_cast(ushort, (_Float16)a.x), __builtin_bit_cast(ushort, (_Float16)a.y),
                  __builtin_bit_cast(ushort, (_Float16)a.z), __builtin_bit_cast(ushort, (_Float16)a.w),
                  __builtin_bit_cast(ushort, (_Float16)b.x), __builtin_bit_cast(ushort, (_Float16)b.y),
                  __builtin_bit_cast(ushort, (_Float16)b.z), __builtin_bit_cast(ushort, (_Float16)b.w)};
    *(ushort8v*)(q + i * 4) = h;
  }
  {
#pragma clang fp contract(off)
    cblk[row][blk] = ((r[0] + r[1]) + (r[2] + r[3])) + ((r[4] + r[5]) + (r[6] + r[7]));
  }
  __syncthreads();
  if (t < 64) {
#pragma clang fp contract(off)
    csq[r0 + t] = (cblk[t][0] + cblk[t][1]) + (cblk[t][2] + cblk[t][3]);
  }
}

// ------------- screening GEMM (fp16 single, K=512) -------------
// R14 (replay-proven): L2-aware remap, epilogue v2, single-buffer gload_lds,
// 512 threads / 8 waves per 128x128 tile -> 4 blocks x 8 waves = 32 waves/CU.
__global__ __launch_bounds__(512, 8)
void vq_screen16_kernel(const ushort* __restrict__ Axp, const ushort* __restrict__ Bfp,
                        const float* __restrict__ csq, ull* __restrict__ keys) {
  __shared__ ushort AS[128 * 64];
  __shared__ ushort BS[128 * 64];
  __shared__ ull mb[128][2][2];

  const int t = threadIdx.x;
  const int L = t & 63;
  const int w = t >> 6;            // 0..7
  const int wr = (w & 3) * 32;     // row group (4 x 32 rows)
  const int wc = (w >> 2) * 64;    // col half (2 x 64 cols)
  const int seg = L >> 4;
  const int l15 = L & 15;

  // L2-aware bijective remap: bid -> (xcd, rg, cbi, ri)
  const int bid = blockIdx.x;
  const int xcd = bid & 7;
  const int loc = bid >> 3;            // 0..1023
  const int ri  = loc & 7;
  const int cbi = (loc >> 3) & 7;
  const int rg  = loc >> 6;            // 0..15
  const int rb  = rg * 8 + ri;         // 0..127
  const int cb  = xcd * 8 + cbi;       // 0..63
  const size_t r0 = (size_t)rb * 128, c0 = (size_t)cb * 128;

  // staging: wave w covers A rows [w*16, w*16+16) and B rows likewise.
  // lane l -> dest row (issue base + l>>3), dest granule l&7; source supplies
  // the inverse-swizzled granule (l&7)^(l>>3) so swizzled READS stay valid.
  const int lrow = L >> 3;
  const int lgr = (L & 7) ^ lrow;
  const ushort* srcA0 = Axp + (r0 + w * 16 + lrow) * DD + lgr * 8;
  const ushort* srcB0 = Bfp + (c0 + w * 16 + lrow) * DD + lgr * 8;

  // loop-invariant LDS read offsets
  int aoff[2][2], boff[2][4];
#pragma unroll
  for (int s = 0; s < 2; ++s) {
    const int kcol = s * 4 + seg;
#pragma unroll
    for (int m = 0; m < 2; ++m) {
      const int rl = wr + m * 16 + l15;
      aoff[s][m] = rl * 64 + ((kcol * 8) ^ ((rl & 7) * 8));
    }
#pragma unroll
    for (int n = 0; n < 4; ++n) {
      const int cl = wc + n * 16 + l15;
      boff[s][n] = cl * 64 + ((kcol * 8) ^ ((cl & 7) * 8));
    }
  }

  floatx4 acc[2][4];
#pragma unroll
  for (int m = 0; m < 2; ++m)
#pragma unroll
    for (int n = 0; n < 4; ++n) acc[m][n] = (floatx4){0.f, 0.f, 0.f, 0.f};

  for (int kc = 0; kc < 8; ++kc) {
    if (kc) __syncthreads();  // all readers done before clobbering the buffer
#pragma unroll
    for (int j = 0; j < 2; ++j) {
      gl_lds16(srcA0 + (size_t)j * 8 * DD + kc * 64, &AS[(w * 16 + j * 8) * 64]);
      gl_lds16(srcB0 + (size_t)j * 8 * DD + kc * 64, &BS[(w * 16 + j * 8) * 64]);
    }
    __syncthreads();  // vmcnt(0)+lgkmcnt(0) drain: staged data visible

#pragma unroll
    for (int s = 0; s < 2; ++s) {
      half8v af[2], bf[4];
#pragma unroll
      for (int m = 0; m < 2; ++m) af[m] = *(const half8v*)&AS[aoff[s][m]];
#pragma unroll
      for (int n = 0; n < 4; ++n) bf[n] = *(const half8v*)&BS[boff[s][n]];
#pragma unroll
      for (int m = 0; m < 2; ++m)
#pragma unroll
        for (int n = 0; n < 4; ++n)
          acc[m][n] = __builtin_amdgcn_mfma_f32_16x16x32_f16(af[m], bf[n], acc[m][n], 0, 0, 0);
    }
  }

  // ---- epilogue v2: float-domain per-row best-2, owner-writes via ballot ----
  float cq[4];
#pragma unroll
  for (int n = 0; n < 4; ++n) cq[n] = csq[c0 + wc + n * 16 + l15];
  const float INF = __builtin_inff();

#pragma unroll
  for (int m = 0; m < 2; ++m) {
#pragma unroll
    for (int i = 0; i < 4; ++i) {
      float q0 = __builtin_fmaf(-2.f, acc[m][0][i], cq[0]);
      float q1 = __builtin_fmaf(-2.f, acc[m][1][i], cq[1]);
      float q2 = __builtin_fmaf(-2.f, acc[m][2][i], cq[2]);
      float q3 = __builtin_fmaf(-2.f, acc[m][3][i], cq[3]);
      const int rl = wr + m * 16 + seg * 4 + i;

      // best-1 across the 16 lanes (f32 shuffles)
      float qm = fminf(fminf(q0, q1), fminf(q2, q3));
#pragma unroll
      for (int mask = 1; mask <= 8; mask <<= 1) qm = fminf(qm, __shfl_xor(qm, mask, 64));
      int n1 = (q0 == qm) ? 0 : (q1 == qm) ? 1 : (q2 == qm) ? 2 : (q3 == qm) ? 3 : 4;
      ull bal = __ballot(n1 < 4);
      int fl = __ffsll((bal >> (seg * 16)) & 0xFFFFull) - 1;
      const bool own1 = (l15 == fl);
      if (own1) {
        int col = (int)c0 + wc + n1 * 16 + l15;
        mb[rl][w >> 2][0] = ((ull)fsort(qm) << 32) | (uint32_t)col;
      }
      // best-2: owner masks its matched element, repeat
      float e0 = q0, e1 = q1, e2 = q2, e3 = q3;
      if (own1) {
        if (n1 == 0) e0 = INF; else if (n1 == 1) e1 = INF;
        else if (n1 == 2) e2 = INF; else e3 = INF;
      }
      float q2m = fminf(fminf(e0, e1), fminf(e2, e3));
#pragma unroll
      for (int mask = 1; mask <= 8; mask <<= 1) q2m = fminf(q2m, __shfl_xor(q2m, mask, 64));
      int n2 = (e0 == q2m) ? 0 : (e1 == q2m) ? 1 : (e2 == q2m) ? 2 : (e3 == q2m) ? 3 : 4;
      ull bal2 = __ballot(n2 < 4);
      int fl2 = __ffsll((bal2 >> (seg * 16)) & 0xFFFFull) - 1;
      if (l15 == fl2) {
        int col = (int)c0 + wc + n2 * 16 + l15;
        mb[rl][w >> 2][1] = ((ull)fsort(q2m) << 32) | (uint32_t)col;
      }
    }
  }
  __syncthreads();
  if (t < 128) {
    ull a1 = mb[t][0][0], a2 = mb[t][0][1];
    ull b1 = mb[t][1][0], b2 = mb[t][1][1];
    ull k1, k2;
    if (a1 < b1) { k1 = a1; k2 = umin64(a2, b1); }
    else { k1 = b1; k2 = umin64(b2, a1); }
    keys[(r0 + t) * 128 + cb * 2 + 0] = k1;
    keys[(r0 + t) * 128 + cb * 2 + 1] = k2;
  }
}

// ------- reduce: ballot margin-count, skip-if-unique, wave-parallel rescore -------
__global__ __launch_bounds__(256)
void vq_reduce_kernel(const float* __restrict__ X, const float* __restrict__ CB,
                      const float* __restrict__ csq, const ull* __restrict__ keys,
                      float* __restrict__ out) {
  __shared__ int bidx[4];
  const int t = threadIdx.x;
  const int L = t & 63;
  const int w = t >> 6;
  const size_t row = (size_t)blockIdx.x * 4 + w;
  ulonglong2 kk = *(const ulonglong2*)(keys + row * 128 + L * 2);

  ull kmin = umin64(kk.x, kk.y);
#pragma unroll
  for (int m = 32; m; m >>= 1) {
    ull o = __shfl_xor(kmin, m, 64);
    if (o < kmin) kmin = o;
  }
  const float qcut = funsort((uint32_t)(kmin >> 32)) + MARGIN;

  // candidates within margin (kmin always qualifies)
  const bool q0 = funsort((uint32_t)(kk.x >> 32)) <= qcut;
  const bool q1 = funsort((uint32_t)(kk.y >> 32)) <= qcut;
  const ull b0 = __ballot(q0);
  const ull b1 = __ballot(q1);
  const int total = __popcll(b0) + __popcll(b1);

  int winner;
  if (total <= 1) {
    // unique candidate: screen error (<~0.1) << MARGIN -> winner is exact argmin
    winner = (int)(kmin & 0xffffffffu);
  } else {
    // wave-parallel exact fp32 rescore; x_sq is row-constant and drops out,
    // so compare q = c_sq - 2*dot.
    const float* xp = X + row * DD;
    const float4 xa = ((const float4*)xp)[L * 2];
    const float4 xb = ((const float4*)xp)[L * 2 + 1];
    ull bestE = ~0ull;
#pragma unroll
    for (int pass = 0; pass < 2; ++pass) {
      ull mask = pass ? b1 : b0;
      while (mask) {
        const int lane = __ffsll(mask) - 1;
        mask &= mask - 1;
        const ull key = __shfl(pass ? kk.y : kk.x, lane, 64);
        const int idx = (int)(key & 0xffffffffu);
        const float* cp = CB + (size_t)idx * DD;
        const float4 ca = ((const float4*)cp)[L * 2];
        const float4 cbv = ((const float4*)cp)[L * 2 + 1];
        float p = 0.f;
        p = __builtin_fmaf(xa.x, ca.x, p);
        p = __builtin_fmaf(xa.y, ca.y, p);
        p = __builtin_fmaf(xa.z, ca.z, p);
        p = __builtin_fmaf(xa.w, ca.w, p);
        p = __builtin_fmaf(xb.x, cbv.x, p);
        p = __builtin_fmaf(xb.y, cbv.y, p);
        p = __builtin_fmaf(xb.z, cbv.z, p);
        p = __builtin_fmaf(xb.w, cbv.w, p);
#pragma unroll
        for (int m = 32; m; m >>= 1) p += __shfl_xor(p, m, 64);
        const float q = csq[idx] - 2.0f * p;
        const ull ek = ((ull)fsort(q) << 32) | (uint32_t)idx;
        bestE = umin64(bestE, ek);
      }
    }
    winner = (int)(bestE & 0xffffffffu);
  }
  if (L == 0) bidx[w] = winner;
  __syncthreads();

  const size_t r0 = (size_t)blockIdx.x * 4;
#pragma unroll
  for (int it = 0; it < 2; ++it) {
    int idx = t + it * 256;
    int rw = idx >> 7, c4 = idx & 127;
    float4 v = *(const float4*)(CB + (size_t)bidx[rw] * DD + c4 * 4);
    *(float4*)(out + (r0 + rw) * DD + c4 * 4) = v;
  }
}

// =================== fallback path (round-2, ws-free, replay-proven) ===================
constexpr int FBM = 128, FBN = 128, FBK = 32, FNT = 256;
constexpr int FKSPLIT = 4;
constexpr int FKPB = KK / FKSPLIT;

__global__ __launch_bounds__(FNT)
void vq_partial_kernel(const float* __restrict__ X, const float* __restrict__ CB,
                       float* __restrict__ keyout) {
  __shared__ float Xs[FBK][FBM + 4];
  __shared__ float Cs[FBK][FBN + 4];
  __shared__ float xblk[FBM][4];
  __shared__ float cblk[FBN][4];
  __shared__ float xsq[FBM];
  __shared__ float csq[FBN];

  const int t = threadIdx.x;
  const int tx = t & 15;
  const int ty = t >> 4;
  const int bid = blockIdx.x;
  const int xcd = bid & 7;
  const int loc = bid >> 3;
  const int ksplit = xcd >> 1;
  const int rowblk = (xcd & 1) * 64 + loc;
  const long r0 = (long)rowblk * FBM;
  const int kbase = ksplit * FKPB;

#pragma unroll
  for (int it = 0; it < 2; ++it) {
    int task = t + it * FNT;
    int row = task >> 2, blk = task & 3;
    xblk[row][blk] = pairwise128_sq(X + (r0 + row) * DD + blk * 128);
  }
  __syncthreads();
  if (t < FBM) {
#pragma clang fp contract(off)
    xsq[t] = (xblk[t][0] + xblk[t][1]) + (xblk[t][2] + xblk[t][3]);
  }

  uint64_t bestKey[8];
#pragma unroll
  for (int i = 0; i < 8; ++i) bestKey[i] = ~0ull;

  float4 xr[4], cr[4];
  for (int kt = 0; kt < FKPB / FBN; ++kt) {
    const int k0 = kbase + kt * FBN;
    __syncthreads();
#pragma unroll
    for (int it = 0; it < 4; ++it) {
      int idx = t + it * FNT;
      int row = idx >> 3, dg = (idx & 7) * 4;
      xr[it] = *(const float4*)(X + (r0 + row) * DD + dg);
      cr[it] = *(const float4*)(CB + (long)(k0 + row) * DD + dg);
    }
#pragma unroll
    for (int it = 0; it < 2; ++it) {
      int task = t + it * FNT;
      int cw = task >> 2, blk = task & 3;
      cblk[cw][blk] = pairwise128_sq(CB + (long)(k0 + cw) * DD + blk * 128);
    }
    __syncthreads();
    if (t < FBN) {
#pragma clang fp contract(off)
      csq[t] = (cblk[t][0] + cblk[t][1]) + (cblk[t][2] + cblk[t][3]);
    }

    float acc[8][8];
#pragma unroll
    for (int i = 0; i < 8; ++i)
#pragma unroll
      for (int j = 0; j < 8; ++j) acc[i][j] = 0.0f;

    for (int dc = 0; dc < DD; dc += FBK) {
#pragma unroll
      for (int it = 0; it < 4; ++it) {
        int idx = t + it * FNT;
        int row = idx >> 3, dg = (idx & 7) * 4;
        Xs[dg + 0][row] = xr[it].x; Xs[dg + 1][row] = xr[it].y;
        Xs[dg + 2][row] = xr[it].z; Xs[dg + 3][row] = xr[it].w;
        Cs[dg + 0][row] = cr[it].x; Cs[dg + 1][row] = cr[it].y;
        Cs[dg + 2][row] = cr[it].z; Cs[dg + 3][row] = cr[it].w;
      }
      if (dc + FBK < DD) {
#pragma unroll
        for (int it = 0; it < 4; ++it) {
          int idx = t + it * FNT;
          int row = idx >> 3, dg = (idx & 7) * 4 + dc + FBK;
          xr[it] = *(const float4*)(X + (r0 + row) * DD + dg);
          cr[it] = *(const float4*)(CB + (long)(k0 + row) * DD + dg);
        }
      }
      __syncthreads();
#pragma unroll 4
      for (int d = 0; d < FBK; ++d) {
        const float4 xa0 = *(const float4*)&Xs[d][ty * 4];
        const float4 xa1 = *(const float4*)&Xs[d][64 + ty * 4];
        const float4 cb0 = *(const float4*)&Cs[d][tx * 4];
        const float4 cb1 = *(const float4*)&Cs[d][64 + tx * 4];
        const float xv[8] = {xa0.x, xa0.y, xa0.z, xa0.w, xa1.x, xa1.y, xa1.z, xa1.w};
        const float cv[8] = {cb0.x, cb0.y, cb0.z, cb0.w, cb1.x, cb1.y, cb1.z, cb1.w};
#pragma unroll
        for (int i = 0; i < 8; ++i)
#pragma unroll
          for (int j = 0; j < 8; ++j)
            acc[i][j] = __builtin_fmaf(xv[i], cv[j], acc[i][j]);
      }
      __syncthreads();
    }
    {
#pragma clang fp contract(off)
#pragma unroll
      for (int i = 0; i < 8; ++i) {
        int rl = (i < 4) ? (ty * 4 + i) : (64 + ty * 4 + (i - 4));
        float xsv = xsq[rl];
#pragma unroll
        for (int j = 0; j < 8; ++j) {
          int cl = (j < 4) ? (tx * 4 + j) : (64 + tx * 4 + (j - 4));
          float m = 2.0f * acc[i][j];
          float t1 = xsv - m;
          float dist = t1 + csq[cl];
          uint64_t key = ((uint64_t)fsort(dist) << 32) | (uint32_t)(k0 + cl);
          if (key < bestKey[i]) bestKey[i] = key;
        }
      }
    }
  }
#pragma unroll
  for (int i = 0; i < 8; ++i) {
    ull k = bestKey[i];
#pragma unroll
    for (int m = 1; m <= 8; m <<= 1) {
      ull o = __shfl_xor(k, m, 64);
      if (o < k) k = o;
    }
    if (tx == 0) {
      int rl = (i < 4) ? (ty * 4 + i) : (64 + ty * 4 + (i - 4));
      *(ull*)(keyout + (r0 + rl) * DD + ksplit * 2) = k;
    }
  }
}

__global__ __launch_bounds__(FNT)
void vq_reduce_gather_kernel(const float* __restrict__ CB, float* __restrict__ out) {
  __shared__ int bidx[32];
  const int t = threadIdx.x;
  const long r0 = (long)blockIdx.x * 32;
  if (t < 32) {
    const ull* kp = (const ull*)(out + (r0 + t) * DD);
    ull k = kp[0];
#pragma unroll
    for (int s = 1; s < FKSPLIT; ++s) k = umin64(k, kp[s]);
    bidx[t] = (int)(k & 0xffffffffu);
  }
  __syncthreads();
#pragma unroll
  for (int it = 0; it < 16; ++it) {
    int idx = t + it * FNT;
    int row = idx >> 7, c4 = idx & 127;
    const float4 v = *(const float4*)(CB + (long)bidx[row] * DD + c4 * 4);
    *(float4*)(out + (r0 + row) * DD + c4 * 4) = v;
  }
}

extern "C" void kernel_launch(void* const* d_in, const int* in_sizes, int n_in,
                              void* d_out, int out_size, void* d_ws, size_t ws_size,
                              hipStream_t stream) {
  const float* X = (const float*)d_in[0];   // [16384, 512]
  const float* CB = (const float*)d_in[1];  // [8192, 512]
  float* out = (float*)d_out;

  if (ws_size >= WS_NEEDED) {
    ushort* Axp = (ushort*)d_ws;
    ushort* Bfp = Axp + AX_ELEMS;
    float* csqp = (float*)(Bfp + BF_ELEMS);
    ull* keys = (ull*)(csqp + KK);
    hipLaunchKernelGGL(cast16_kernel, dim3(NROWS * DD / 4 / 256), dim3(256), 0, stream, X, Axp);
    hipLaunchKernelGGL(castB_csq_kernel, dim3(KK / 64), dim3(256), 0, stream, CB, Bfp, csqp);
    hipLaunchKernelGGL(vq_screen16_kernel, dim3((NROWS / 128) * (KK / 128)), dim3(512), 0, stream,
                       Axp, Bfp, csqp, keys);
    hipLaunchKernelGGL(vq_reduce_kernel, dim3(NROWS / 4), dim3(256), 0, stream,
                       X, CB, csqp, keys, out);
  } else {
    hipLaunchKernelGGL(vq_partial_kernel, dim3(512), dim3(FNT), 0, stream, X, CB, out);
    hipLaunchKernelGGL(vq_reduce_gather_kernel, dim3(NROWS / 32), dim3(FNT), 0, stream, CB, out);
  }
}